// Round 9
// baseline (458.183 us; speedup 1.0000x reference)
//
#include <hip/hip_runtime.h>
#include <hip/hip_bf16.h>
#include <hip/hip_fp16.h>

// Problem constants
#define NN    32768
#define EE    98304
#define FN    32
#define FEDGE 16
#define DD    64
#define OUTD  16
#define GG    64
#define EPSL  1e-5f
#define EB    128      // edges per conv block

typedef __attribute__((ext_vector_type(8))) _Float16 f16x8;
typedef __attribute__((ext_vector_type(4))) float f32x4;

// ---------------------------------------------------------------------------
// fc1 + agginit1 fused: hx = x@fc1_w+fc1_b ; agg1 = hx@root1 + bias1
// ---------------------------------------------------------------------------
__global__ __launch_bounds__(256) void k_fc1agg(const float* __restrict__ x,
                                                const float* __restrict__ w1,
                                                const float* __restrict__ b1,
                                                const float* __restrict__ root,
                                                const float* __restrict__ rbias,
                                                float* __restrict__ hx,
                                                float* __restrict__ agg) {
    __shared__ float rowbuf[4][64];
    int t = threadIdx.x, d = t & 63, wv = t >> 6;
    int n = blockIdx.x * 4 + wv;
    const float* xr = x + n * FN;
    float acc = b1[d];
    #pragma unroll
    for (int i = 0; i < FN; ++i) acc += xr[i] * w1[i * DD + d];
    hx[n * DD + d] = acc;
    rowbuf[wv][d] = acc;
    __syncthreads();
    float a0 = rbias[d], a1 = 0.f, a2 = 0.f, a3 = 0.f;
    #pragma unroll
    for (int i = 0; i < DD; i += 4) {
        a0 += rowbuf[wv][i]     * root[i * DD + d];
        a1 += rowbuf[wv][i + 1] * root[(i + 1) * DD + d];
        a2 += rowbuf[wv][i + 2] * root[(i + 2) * DD + d];
        a3 += rowbuf[wv][i + 3] * root[(i + 3) * DD + d];
    }
    agg[n * DD + d] = (a0 + a1) + (a2 + a3);
}

// ---------------------------------------------------------------------------
// edge MLP (+ fused w2 prep on blocks 0..64):
//   het[k][e] = relu(ea[e][:16] @ w1 + b1) (fp16),  het[64][e] = 1.0
//   w2t[s][o][i] = fp16(slice_s[i][o]);  slice 64 = b2.  (plain layout)
// ---------------------------------------------------------------------------
__global__ __launch_bounds__(256) void k_mlpprep(const float* __restrict__ ea,
                                                 const float* __restrict__ w1,
                                                 const float* __restrict__ b1,
                                                 __half* __restrict__ het,
                                                 const float* __restrict__ w2,
                                                 const float* __restrict__ b2,
                                                 __half* __restrict__ w2t) {
    __shared__ float eas[256][17];
    int t = threadIdx.x;
    int e0 = blockIdx.x * 256;
    const float4* src = (const float4*)(ea + e0 * FEDGE);
    #pragma unroll
    for (int j = 0; j < 4; ++j) {
        float4 v = src[t + 256 * j];
        int f = (t + 256 * j) * 4;
        int e = f >> 4, i = f & 15;
        eas[e][i] = v.x; eas[e][i + 1] = v.y; eas[e][i + 2] = v.z; eas[e][i + 3] = v.w;
    }
    // fused prep (65 of the 384 blocks)
    if (blockIdx.x < 65) {
        int s = blockIdx.x;
        const float* psrc = (s < 64) ? (w2 + s * 4096) : b2;
        int o = t >> 2;
        #pragma unroll
        for (int j = 0; j < 16; ++j) {
            int i = (t & 3) * 16 + j;
            w2t[s * 4096 + o * 64 + i] = __float2half_rn(psrc[i * 64 + o]);
        }
    }
    __syncthreads();
    int e = e0 + t;
    float a[FEDGE];
    #pragma unroll
    for (int i = 0; i < FEDGE; ++i) a[i] = eas[t][i];
    for (int k = 0; k < DD; ++k) {
        float acc = b1[k];
        #pragma unroll
        for (int i = 0; i < FEDGE; ++i) acc += a[i] * w1[i * DD + k];
        acc = fmaxf(acc, 0.0f);
        het[k * EE + e] = __float2half_rn(acc);
    }
    het[DD * EE + e] = __float2half_rn(1.0f);
}

// ---------------------------------------------------------------------------
// conv (MFMA f16), barrier-free main loop:
//   block = 128 edges x 64 outputs, grid = 768 = 3 blocks/CU.
//   waves 2x2 (wm = edge half 64, wn = output half 32).
//   B fragments loaded straight from global (L2-resident w2t) into a named
//   2-deep register double buffer; hs (h tile) in LDS (one barrier total).
// Block 0 additionally zeroes `zbuf[0..zn)` (stats/pool/cnt init).
// ---------------------------------------------------------------------------
__global__ __launch_bounds__(256, 3) void k_conv(const float* __restrict__ xs,
                                                 const __half* __restrict__ het,
                                                 const __half* __restrict__ w2t,
                                                 const int* __restrict__ ei,
                                                 float* __restrict__ agg,
                                                 float* __restrict__ zbuf,
                                                 int zn) {
    __shared__ __align__(16) __half hs[65 * EB];      // 16.64 KB

    const int t   = threadIdx.x;
    const int l   = t & 63;
    const int w   = t >> 6;
    const int wm  = w & 1;                 // edge half (0/1)
    const int wn  = w >> 1;                // output half (0/1)
    const int q   = l >> 4;
    const int r16 = l & 15;
    const int e0  = blockIdx.x * EB;

    if (blockIdx.x == 0) {
        for (int i = t; i < zn; i += 256) zbuf[i] = 0.0f;
    }

    // ---- xs fragments -> fp16 registers: 4 sub-tiles x 16 k-vals ----
    __half2 xh[4][8];
    #pragma unroll
    for (int sm = 0; sm < 4; ++sm) {
        int em = e0 + wm * 64 + sm * 16 + r16;
        int sn = ei[em];                              // src node
        const float4* xr = (const float4*)(xs + sn * DD);
        float4 a0 = xr[q * 2], a1 = xr[q * 2 + 1];
        float4 b0 = xr[8 + q * 2], b1 = xr[8 + q * 2 + 1];
        xh[sm][0] = __floats2half2_rn(a0.x, a0.y);
        xh[sm][1] = __floats2half2_rn(a0.z, a0.w);
        xh[sm][2] = __floats2half2_rn(a1.x, a1.y);
        xh[sm][3] = __floats2half2_rn(a1.z, a1.w);
        xh[sm][4] = __floats2half2_rn(b0.x, b0.y);
        xh[sm][5] = __floats2half2_rn(b0.z, b0.w);
        xh[sm][6] = __floats2half2_rn(b1.x, b1.y);
        xh[sm][7] = __floats2half2_rn(b1.z, b1.w);
    }

    // ---- stage h tile [65][EB] fp16 into LDS (65 rows x 16 uint4) ----
    for (int j = t; j < 65 * 16; j += 256) {
        int row = j >> 4, col = j & 15;
        ((uint4*)hs)[j] = ((const uint4*)(het + row * EE + e0))[col];
    }
    __syncthreads();                                  // only barrier in kernel

    // per-lane B-fragment element offsets (plain [o][i] layout)
    int boffe[2][2];
    #pragma unroll
    for (int j = 0; j < 2; ++j)
        #pragma unroll
        for (int p = 0; p < 2; ++p)
            boffe[j][p] = ((wn * 2 + j) * 16 + r16) * 64 + p * 32 + q * 8;

    f32x4 acc[4][2];
    #pragma unroll
    for (int sm = 0; sm < 4; ++sm)
        #pragma unroll
        for (int j = 0; j < 2; ++j)
            acc[sm][j] = (f32x4){0.f, 0.f, 0.f, 0.f};

    auto loadB = [&](f16x8 (&B)[2][2], const __half* wp) {
        #pragma unroll
        for (int j = 0; j < 2; ++j)
            #pragma unroll
            for (int p = 0; p < 2; ++p)
                B[j][p] = *(const f16x8*)(wp + boffe[j][p]);
    };

    auto compute = [&](int s, f16x8 (&B)[2][2]) {
        __half2 hh[4];
        #pragma unroll
        for (int sm = 0; sm < 4; ++sm)
            hh[sm] = __half2half2(hs[s * EB + wm * 64 + sm * 16 + r16]);
        #pragma unroll
        for (int p = 0; p < 2; ++p)
            #pragma unroll
            for (int sm = 0; sm < 4; ++sm) {
                union { f16x8 v; __half2 h2[4]; } af;
                #pragma unroll
                for (int jj = 0; jj < 4; ++jj)
                    af.h2[jj] = __hmul2(hh[sm], xh[sm][p * 4 + jj]);
                #pragma unroll
                for (int j = 0; j < 2; ++j)
                    acc[sm][j] = __builtin_amdgcn_mfma_f32_16x16x32_f16(
                        af.v, B[j][p], acc[sm][j], 0, 0, 0);
            }
    };

    f16x8 BA[2][2], BB[2][2];
    const __half* wp = w2t;
    loadB(BA, wp);                                    // slice 0
    for (int s = 0; s < 64; s += 2) {
        loadB(BB, wp + 4096);                         // slice s+1
        compute(s, BA);
        loadB(BA, wp + 8192);                         // slice s+2 (<= 64)
        compute(s + 1, BB);
        wp += 8192;
    }
    compute(64, BA);

    // ---- epilogue: C layout col=r16, row=q*4+rr ----
    #pragma unroll
    for (int sm = 0; sm < 4; ++sm) {
        #pragma unroll
        for (int rr = 0; rr < 4; ++rr) {
            int em = e0 + wm * 64 + sm * 16 + q * 4 + rr;
            int dn = ei[EE + em];                              // dst node
            float* ar = agg + dn * DD + wn * 32 + r16;
            #pragma unroll
            for (int j = 0; j < 2; ++j)
                atomicAdd(ar + j * 16, acc[sm][j][rr]);
        }
    }
}

// ---------------------------------------------------------------------------
// LN reduce: global sum / sum-of-squares
// ---------------------------------------------------------------------------
__global__ __launch_bounds__(256) void k_lnred(const float* __restrict__ v,
                                               float* __restrict__ stats) {
    int t = threadIdx.x;
    int base = blockIdx.x * 4096 + t;
    float s = 0.0f, s2 = 0.0f;
    #pragma unroll
    for (int j = 0; j < 16; ++j) {
        float x = v[base + j * 256];
        s += x; s2 += x * x;
    }
    #pragma unroll
    for (int off = 32; off > 0; off >>= 1) {
        s  += __shfl_down(s, off, 64);
        s2 += __shfl_down(s2, off, 64);
    }
    __shared__ float ps[8];
    int w = t >> 6;
    if ((t & 63) == 0) { ps[w] = s; ps[4 + w] = s2; }
    __syncthreads();
    if (t == 0) {
        atomicAdd(&stats[0], ps[0] + ps[1] + ps[2] + ps[3]);
        atomicAdd(&stats[1], ps[4] + ps[5] + ps[6] + ps[7]);
    }
}

// ---------------------------------------------------------------------------
// lnapply1 + agginit2 fused: h1 = relu(norm(agg1raw)) in place;
// agg2 = h1@root2 + bias2.  (reference divides by (std + eps))
// ---------------------------------------------------------------------------
__global__ __launch_bounds__(256) void k_lnagg(float* __restrict__ h1,
                                               const float* __restrict__ stats,
                                               const float* __restrict__ gw,
                                               const float* __restrict__ gb,
                                               const float* __restrict__ root,
                                               const float* __restrict__ rbias,
                                               float* __restrict__ agg2) {
    const float M = (float)(NN * DD);
    float mean = stats[0] / M;
    float var  = stats[1] / M - mean * mean;
    float rden = 1.0f / (sqrtf(fmaxf(var, 0.0f)) + EPSL);
    __shared__ float rowbuf[4][64];
    int t = threadIdx.x, d = t & 63, wv = t >> 6;
    int n = blockIdx.x * 4 + wv;
    float v = h1[n * DD + d];
    float h = fmaxf((v - mean) * rden * gw[d] + gb[d], 0.0f);
    h1[n * DD + d] = h;
    rowbuf[wv][d] = h;
    __syncthreads();
    float a0 = rbias[d], a1 = 0.f, a2 = 0.f, a3 = 0.f;
    #pragma unroll
    for (int i = 0; i < DD; i += 4) {
        a0 += rowbuf[wv][i]     * root[i * DD + d];
        a1 += rowbuf[wv][i + 1] * root[(i + 1) * DD + d];
        a2 += rowbuf[wv][i + 2] * root[(i + 2) * DD + d];
        a3 += rowbuf[wv][i + 3] * root[(i + 3) * DD + d];
    }
    agg2[n * DD + d] = (a0 + a1) + (a2 + a3);
}

// ---------------------------------------------------------------------------
// lnapply2 + pool fused
// ---------------------------------------------------------------------------
__global__ __launch_bounds__(256) void k_lnpool(const float* __restrict__ v,
                                                const float* __restrict__ stats,
                                                const float* __restrict__ gw,
                                                const float* __restrict__ gb,
                                                const int* __restrict__ batch,
                                                float* __restrict__ pool,
                                                float* __restrict__ cnt) {
    const float M = (float)(NN * DD);
    float mean = stats[0] / M;
    float var  = stats[1] / M - mean * mean;
    float rden = 1.0f / (sqrtf(fmaxf(var, 0.0f)) + EPSL);
    int t = threadIdx.x;
    int d = t & 63;
    int ln = t >> 6;
    int n0 = blockIdx.x * 256;
    float gwd = gw[d] * rden, gbd = gb[d];
    float s = 0.0f, sc = 0.0f;
    int cur = batch[n0 + ln];
    for (int j = 0; j < 64; ++j) {
        int n = n0 + ln + j * 4;
        int b = batch[n];
        if (b != cur) {
            atomicAdd(&pool[cur * DD + d], s);
            if (d == 0) atomicAdd(&cnt[cur], sc);
            s = 0.0f; sc = 0.0f; cur = b;
        }
        s  += fmaxf((v[n * DD + d] - mean) * gwd + gbd, 0.0f);
        sc += 1.0f;
    }
    atomicAdd(&pool[cur * DD + d], s);
    if (d == 0) atomicAdd(&cnt[cur], sc);
}

// ---------------------------------------------------------------------------
// fc2
// ---------------------------------------------------------------------------
__global__ __launch_bounds__(256) void k_fc2(const float* __restrict__ pool,
                                             const float* __restrict__ cnt,
                                             const float* __restrict__ w,
                                             const float* __restrict__ b,
                                             float* __restrict__ out) {
    int t = threadIdx.x;
    int o = t & 15;
    int g0 = t >> 4;
    #pragma unroll
    for (int gg = 0; gg < 4; ++gg) {
        int g = g0 + gg * 16;
        float inv = 1.0f / fmaxf(cnt[g], 1.0f);
        float acc = b[o];
        #pragma unroll
        for (int d = 0; d < DD; ++d)
            acc += pool[g * DD + d] * inv * w[d * OUTD + o];
        out[g * OUTD + o] = acc;
    }
}

// ---------------------------------------------------------------------------
extern "C" void kernel_launch(void* const* d_in, const int* in_sizes, int n_in,
                              void* d_out, int out_size, void* d_ws, size_t ws_size,
                              hipStream_t stream) {
    const float* x       = (const float*)d_in[0];
    const float* ea      = (const float*)d_in[1];
    const int*   ei      = (const int*)d_in[2];
    const int*   batch   = (const int*)d_in[3];
    const float* fc1_w   = (const float*)d_in[4];
    const float* fc1_b   = (const float*)d_in[5];
    const float* e1w1    = (const float*)d_in[6];
    const float* e1b1    = (const float*)d_in[7];
    const float* e1w2    = (const float*)d_in[8];
    const float* e1b2    = (const float*)d_in[9];
    const float* root1   = (const float*)d_in[10];
    const float* bias1   = (const float*)d_in[11];
    const float* gn1w    = (const float*)d_in[12];
    const float* gn1b    = (const float*)d_in[13];
    const float* e2w1    = (const float*)d_in[14];
    const float* e2b1    = (const float*)d_in[15];
    const float* e2w2    = (const float*)d_in[16];
    const float* e2b2    = (const float*)d_in[17];
    const float* root2   = (const float*)d_in[18];
    const float* bias2   = (const float*)d_in[19];
    const float* gn2w    = (const float*)d_in[20];
    const float* gn2b    = (const float*)d_in[21];
    const float* fc2_w   = (const float*)d_in[22];
    const float* fc2_b   = (const float*)d_in[23];
    float* out = (float*)d_out;

    // workspace layout (bytes)
    char* ws = (char*)d_ws;
    float*  hx    = (float*)(ws);                      // 8 MB; reused as agg2
    float*  agg1  = (float*)(ws + 8388608);            // 8 MB; becomes h1 in place
    __half* het   = (__half*)(ws + 16777216);          // 65*E fp16 = 12.78 MB
    __half* w2t   = (__half*)(ws + 29556736);          // 65*4096 fp16 = 520 KB
    float*  pool  = (float*)(ws + 30089216);           // 16 KB (+cnt 256B +stats 16B)
    float*  cnt   = (float*)(ws + 30105600);
    float*  stats = (float*)(ws + 30105856);
    float*  agg2  = hx;

    // ---- layer 1 ----  (conv1 block 0 zeroes stats[0..1])
    k_fc1agg<<<NN / 4, 256, 0, stream>>>(x, fc1_w, fc1_b, root1, bias1, hx, agg1);
    k_mlpprep<<<EE / 256, 256, 0, stream>>>(ea, e1w1, e1b1, het, e1w2, e1b2, w2t);
    k_conv<<<EE / EB, 256, 0, stream>>>(hx, het, w2t, ei, agg1, stats, 2);
    k_lnred<<<(NN * DD) / 4096, 256, 0, stream>>>(agg1, stats);
    k_lnagg<<<NN / 4, 256, 0, stream>>>(agg1, stats, gn1w, gn1b, root2, bias2, agg2);

    // ---- layer 2 ----  (conv2 block 0 zeroes stats[2..3] + pool + cnt)
    k_mlpprep<<<EE / 256, 256, 0, stream>>>(ea, e2w1, e2b1, het, e2w2, e2b2, w2t);
    k_conv<<<EE / EB, 256, 0, stream>>>(agg1, het, w2t, ei, agg2, pool, 4096 + 64 + 4);
    k_lnred<<<(NN * DD) / 4096, 256, 0, stream>>>(agg2, stats + 2);

    // ---- pool (fused with lnapply2) + fc2 ----
    k_lnpool<<<NN / 256, 256, 0, stream>>>(agg2, stats + 2, gn2w, gn2b, batch, pool, cnt);
    k_fc2<<<1, 256, 0, stream>>>(pool, cnt, fc2_w, fc2_b, out);
}